// Round 12
// baseline (128.896 us; speedup 1.0000x reference)
//
#include <hip/hip_runtime.h>

#define NROWS 8192
#define NBM   512          // k_main blocks
#define NBN   128          // k_norm blocks
// ws layout (bytes) — nothing requires pre-zeroed ws (done counters use modulo)
#define H_OFF     0        // int h[128][4] (2 KB)
#define CNT_OFF   2048     // int cnt[4]
#define CTR_OFF   2064     // int ctr[2]
#define DN1_OFF   2072     // unsigned dn1 (k_norm completion counter, never reset)
#define DN2_OFF   2076     // unsigned dn2 (k_main completion counter, never reset)
#define P2_OFF    4096     // float partial[NBM]
#define IDXNL_OFF 8192     // u16[8192]
#define IDXL_OFF  24576    // u16[8192]
#define CS_OFF    65536    // float cs[128][1024] (512 KB)
#define XN_OFF    1048576  // bf16 xn[8192][256] (4 MB)

typedef __bf16 bf16x8 __attribute__((ext_vector_type(8)));
typedef float  f32x4  __attribute__((ext_vector_type(4)));

__device__ __forceinline__ unsigned short f2bf(float f) {
  unsigned int u = __float_as_uint(f);
  u += 0x7fffu + ((u >> 16) & 1u);
  return (unsigned short)(u >> 16);
}

__device__ __forceinline__ void gl_lds16(const void* g, void* l) {
  __builtin_amdgcn_global_load_lds(
      (const __attribute__((address_space(1))) unsigned int*)g,
      (__attribute__((address_space(3))) unsigned int*)l, 16, 0, 0);
}

// ---- normalize + bf16 + per-chunk hist + class col-sums; LAST block partitions ----
__global__ __launch_bounds__(1024) void k_norm(const float* __restrict__ x,
                                               const int* __restrict__ tgt,
                                               unsigned short* __restrict__ xn,
                                               int* __restrict__ h,
                                               float* __restrict__ cs,
                                               int* __restrict__ cnt,
                                               int* __restrict__ ctr,
                                               unsigned* __restrict__ dn1,
                                               unsigned short* __restrict__ idxNL,
                                               unsigned short* __restrict__ idxL) {
  __shared__ float lx[64][256];    // 64 KB
  __shared__ int lt[64];
  __shared__ int lh[4];
  __shared__ unsigned sold;
  __shared__ int scnt4[4];
  __shared__ int sPL[129];
  const int tid = threadIdx.x, w = tid >> 6, lane = tid & 63;
  const int b = blockIdx.x;
  if (tid < 4) lh[tid] = 0;
  if (tid < 64) lt[tid] = tgt[b * 64 + tid];
#pragma unroll
  for (int i = 0; i < 4; ++i) {
    int r = w * 4 + i;
    int row = b * 64 + r;
    float4 v = reinterpret_cast<const float4*>(x)[row * 64 + lane];
    float ss = v.x * v.x + v.y * v.y + v.z * v.z + v.w * v.w;
#pragma unroll
    for (int off = 32; off; off >>= 1) ss += __shfl_xor(ss, off);
    float iv = 1.0f / fmaxf(sqrtf(ss), 1e-8f);
    float4 nv = make_float4(v.x * iv, v.y * iv, v.z * iv, v.w * iv);
    ushort4 o;
    o.x = f2bf(nv.x); o.y = f2bf(nv.y); o.z = f2bf(nv.z); o.w = f2bf(nv.w);
    reinterpret_cast<ushort4*>(xn)[row * 64 + lane] = o;
    *reinterpret_cast<float4*>(&lx[r][lane * 4]) = nv;
  }
  __syncthreads();
  if (tid < 64) atomicAdd(&lh[lt[tid]], 1);
  {
    const int c = tid >> 8, col = tid & 255;
    float m = 0.0f;
#pragma unroll 8
    for (int r = 0; r < 64; ++r)
      m += (lt[r] == c) ? lx[r][col] : 0.0f;
    cs[b * 1024 + tid] = m;
  }
  __syncthreads();
  if (tid < 4) h[b * 4 + tid] = lh[tid];

  // ---- last-arriving block partitions (modulo counter: no reset needed) ----
  __threadfence();
  if (tid == 0) sold = atomicAdd(dn1, 1u);
  __syncthreads();
  if ((sold % NBN) != NBN - 1) return;
  __threadfence();

  if (tid < 4) scnt4[tid] = 0;
  __syncthreads();
  if (tid < 128) {
    int4 hv = ((const int4*)h)[tid];
    atomicAdd(&scnt4[0], hv.x); atomicAdd(&scnt4[1], hv.y);
    atomicAdd(&scnt4[2], hv.z); atomicAdd(&scnt4[3], hv.w);
  }
  __syncthreads();
  int L = 0;
#pragma unroll
  for (int i = 0; i < 4; ++i) if (scnt4[i] > 0) L = i;
  if (tid < 4) cnt[tid] = scnt4[tid];
  if (tid == 0) { ctr[1] = scnt4[L]; ctr[0] = NROWS - scnt4[L]; }
  if (tid < 128) sPL[tid + 1] = h[tid * 4 + L];
  if (tid == 0) sPL[0] = 0;
  __syncthreads();
  for (int ofs = 1; ofs < 128; ofs <<= 1) {
    int v = 0, i = tid + 1;
    bool act = (tid < 128) && (i > ofs);
    if (act) v = sPL[i - ofs];
    __syncthreads();
    if (act) sPL[i] += v;
    __syncthreads();
  }
  // 16 waves x 8 chunks
#pragma unroll
  for (int k = 0; k < 8; ++k) {
    int c = w + 16 * k;
    int row = c * 64 + lane;
    bool isL = (tgt[row] == L);
    unsigned long long mk = __ballot(isL);
    int rk = __popcll(mk & ((1ull << lane) - 1ull));
    int pl = sPL[c];
    if (isL) idxL[pl + rk] = (unsigned short)row;
    else     idxNL[c * 64 - pl + (lane - rk)] = (unsigned short)row;
  }
}

// ---- rectangle GEMM-reduce (exact R7 body) + last-block final ----
__global__ __launch_bounds__(256, 2) void k_main(const char* __restrict__ xnb,
                                                 const unsigned short* __restrict__ idxNL,
                                                 const unsigned short* __restrict__ idxL,
                                                 const int* __restrict__ ctr,
                                                 const int* __restrict__ cnt,
                                                 const float* __restrict__ cs,
                                                 unsigned* __restrict__ dn2,
                                                 float* __restrict__ partial,
                                                 float* __restrict__ out) {
  __shared__ __align__(16) char sm[65536];   // 2x32KB dbuf
  __shared__ float wred[4];
  __shared__ unsigned sold;
  __shared__ float dsum_s;
  __shared__ float acc8[8];

  const int b = blockIdx.x;
  const int tid = threadIdx.x, w = tid >> 6, lane = tid & 63;
  const int M = ctr[0], NL = ctr[1];
  const int ni = (M + 127) >> 7, nj = (NL + 127) >> 7;
  const int ntiles = ni * nj;

  const int rl = lane >> 3;
  const unsigned pe = ((unsigned)((lane & 7) ^ rl)) << 4;
  const int wr = (w >> 1) * 64, wc = (w & 1) * 64;
  const int l15 = lane & 15;
  const unsigned q16 = ((unsigned)(lane >> 4)) << 4;
  const unsigned key = ((unsigned)(lane & 7)) << 4;
  const int rowj = (lane >> 4) * 4;
  char (*lds)[32768] = (char(*)[32768])sm;

  float bsum = 0.0f;
  for (int t = b; t < ntiles; t += NBM) {
    int bi = t / nj, bj = t - bi * nj;
    int rm = min(128, M - bi * 128);
    int rn = min(128, NL - bj * 128);
    bool full = (rm == 128) && (rn == 128);

    unsigned aoff[4], boff[4];
#pragma unroll
    for (int j = 0; j < 4; ++j) {
      int row = (j * 4 + w) * 8 + rl;
      int ga = idxNL[bi * 128 + min(row, rm - 1)];
      int gb = idxL [bj * 128 + min(row, rn - 1)];
      aoff[j] = (unsigned)ga * 512u + pe;
      boff[j] = (unsigned)gb * 512u + pe;
    }

    auto stage = [&](int buf, int ch) {
      unsigned cbo = (unsigned)(ch << 7);
#pragma unroll
      for (int j = 0; j < 4; ++j)
        gl_lds16(xnb + (size_t)(aoff[j] + cbo), &lds[buf][(j * 4 + w) * 1024]);
#pragma unroll
      for (int j = 0; j < 4; ++j)
        gl_lds16(xnb + (size_t)(boff[j] + cbo), &lds[buf][16384 + (j * 4 + w) * 1024]);
    };

    f32x4 acc[4][4];
#pragma unroll
    for (int m = 0; m < 4; ++m)
#pragma unroll
      for (int n = 0; n < 4; ++n)
        acc[m][n] = (f32x4){0.f, 0.f, 0.f, 0.f};

    auto compute = [&](int buf) {
      const char* bA = lds[buf];
      const char* bB = lds[buf] + 16384;
#pragma unroll
      for (int ks = 0; ks < 2; ++ks) {
        const unsigned q = (unsigned)(ks * 64) + q16;
        bf16x8 af[4], bfr[4];
#pragma unroll
        for (int m = 0; m < 4; ++m)
          af[m] = *(const bf16x8*)(bA + (wr + m * 16 + l15) * 128 + (q ^ key));
#pragma unroll
        for (int n = 0; n < 4; ++n)
          bfr[n] = *(const bf16x8*)(bB + (wc + n * 16 + l15) * 128 + (q ^ key));
        __builtin_amdgcn_s_setprio(1);
#pragma unroll
        for (int m = 0; m < 4; ++m)
#pragma unroll
          for (int n = 0; n < 4; ++n)
            acc[m][n] = __builtin_amdgcn_mfma_f32_16x16x32_bf16(af[m], bfr[n], acc[m][n], 0, 0, 0);
        __builtin_amdgcn_s_setprio(0);
      }
    };

    __syncthreads();
    stage(0, 0); stage(1, 1);
    asm volatile("s_waitcnt vmcnt(8)" ::: "memory");
    __builtin_amdgcn_s_barrier();
    compute(0);
    __builtin_amdgcn_s_barrier();
    stage(0, 2);
    asm volatile("s_waitcnt vmcnt(8)" ::: "memory");
    __builtin_amdgcn_s_barrier();
    compute(1);
    __builtin_amdgcn_s_barrier();
    stage(1, 3);
    asm volatile("s_waitcnt vmcnt(8)" ::: "memory");
    __builtin_amdgcn_s_barrier();
    compute(0);
    __builtin_amdgcn_s_barrier();
    asm volatile("s_waitcnt vmcnt(0)" ::: "memory");
    __builtin_amdgcn_s_barrier();
    compute(1);

    if (full) {
#pragma unroll
      for (int m = 0; m < 4; ++m)
#pragma unroll
        for (int n = 0; n < 4; ++n)
#pragma unroll
          for (int j = 0; j < 4; ++j)
            bsum += fmaxf(acc[m][n][j] - 0.5f, 0.0f);
    } else {
#pragma unroll
      for (int m = 0; m < 4; ++m) {
#pragma unroll
        for (int j = 0; j < 4; ++j) {
          bool rv = (wr + m * 16 + rowj + j) < rm;
#pragma unroll
          for (int n = 0; n < 4; ++n) {
            bool cv = (wc + n * 16 + l15) < rn;
            float g = fmaxf(acc[m][n][j] - 0.5f, 0.0f);
            bsum += (rv && cv) ? g : 0.0f;
          }
        }
      }
    }
  }

#pragma unroll
  for (int off = 32; off; off >>= 1) bsum += __shfl_xor(bsum, off);
  if (lane == 0) wred[w] = bsum;
  __syncthreads();
  if (tid == 0) partial[b] = wred[0] + wred[1] + wred[2] + wred[3];
  __threadfence();
  if (tid == 0) sold = atomicAdd(dn2, 1u);
  __syncthreads();
  if ((sold % NBM) != NBM - 1) return;
  __threadfence();

  // ---- final phase (one block; deterministic values) ----
  {
    float s = partial[tid] + partial[tid + 256];
#pragma unroll
    for (int off = 32; off; off >>= 1) s += __shfl_xor(s, off);
    if (lane == 0) wred[w] = s;
    __syncthreads();
    if (tid == 0) dsum_s = wred[0] + wred[1] + wred[2] + wred[3];
    __syncthreads();

    float m0 = 0, m1 = 0, m2 = 0, m3 = 0;
    for (int bb = 0; bb < 128; ++bb) {
      const float* p = cs + bb * 1024;
      m0 += p[tid]; m1 += p[256 + tid]; m2 += p[512 + tid]; m3 += p[768 + tid];
    }
    float T = m0 + m1 + m2 + m3;
    float vals[8];
    vals[0] = m0 * m0; vals[1] = m1 * m1; vals[2] = m2 * m2; vals[3] = m3 * m3;
    vals[4] = (T - m0) * (T - m0); vals[5] = (T - m1) * (T - m1);
    vals[6] = (T - m2) * (T - m2); vals[7] = (T - m3) * (T - m3);
#pragma unroll
    for (int v = 0; v < 8; ++v) {
      float sv = vals[v];
#pragma unroll
      for (int off = 32; off; off >>= 1) sv += __shfl_xor(sv, off);
      if (lane == 0) wred[w] = sv;
      __syncthreads();
      if (tid == 0) acc8[v] = wred[0] + wred[1] + wred[2] + wred[3];
      __syncthreads();
    }
    if (tid == 0) {
      double dsum = (double)dsum_s;
      double D = (double)NROWS;   // sum of |unit vector|^2
      double same = 0.0;
#pragma unroll
      for (int i = 0; i < 4; ++i) {
        int k = cnt[i];
        if (k > 0) {
          double Pi = 0.5 * (double)k * (double)(k - 1)
                    + 0.5 * (double)(NROWS - k) * (double)(NROWS - k - 1);
          double Si = 0.5 * ((double)acc8[i] + (double)acc8[4 + i] - D);
          same += (Pi - Si) / (double)k;
        }
      }
      out[0] = (float)((same + dsum) / (double)NROWS);
    }
  }
}

extern "C" void kernel_launch(void* const* d_in, const int* in_sizes, int n_in,
                              void* d_out, int out_size, void* d_ws, size_t ws_size,
                              hipStream_t stream) {
  (void)in_sizes; (void)n_in; (void)out_size; (void)ws_size;
  const float* x  = (const float*)d_in[0];
  const int* tgt  = (const int*)d_in[1];
  float* out      = (float*)d_out;
  char* ws        = (char*)d_ws;

  int* h          = (int*)(ws + H_OFF);
  int* cnt        = (int*)(ws + CNT_OFF);
  int* ctr        = (int*)(ws + CTR_OFF);
  unsigned* dn1   = (unsigned*)(ws + DN1_OFF);
  unsigned* dn2   = (unsigned*)(ws + DN2_OFF);
  float* partial  = (float*)(ws + P2_OFF);
  unsigned short* idxNL = (unsigned short*)(ws + IDXNL_OFF);
  unsigned short* idxL  = (unsigned short*)(ws + IDXL_OFF);
  float* cs       = (float*)(ws + CS_OFF);
  unsigned short* xn = (unsigned short*)(ws + XN_OFF);

  k_norm<<<NBN, 1024, 0, stream>>>(x, tgt, xn, h, cs, cnt, ctr, dn1, idxNL, idxL);
  k_main<<<NBM, 256, 0, stream>>>((const char*)xn, idxNL, idxL, ctr, cnt, cs, dn2, partial, out);
}

// Round 13
// 55.380 us; speedup vs baseline: 2.3275x; 2.3275x over previous
//
#include <hip/hip_runtime.h>

#define NROWS 8192
#define NBM   512          // k_main blocks
#define NBN   128          // k_norm blocks
// ws layout (bytes) — nothing requires pre-zeroed ws, no counters at all
#define H_OFF    0         // int h[128][4] (2 KB)       (k_norm)
#define CS_OFF   65536     // float cs[128][1024] (512K) (k_norm)
#define XN_OFF   1048576   // bf16 xn[8192][256] (4 MB)  (k_norm)

typedef __bf16 bf16x8 __attribute__((ext_vector_type(8)));
typedef float  f32x4  __attribute__((ext_vector_type(4)));

__device__ __forceinline__ unsigned short f2bf(float f) {
  unsigned int u = __float_as_uint(f);
  u += 0x7fffu + ((u >> 16) & 1u);
  return (unsigned short)(u >> 16);
}

__device__ __forceinline__ void gl_lds16(const void* g, void* l) {
  __builtin_amdgcn_global_load_lds(
      (const __attribute__((address_space(1))) unsigned int*)g,
      (__attribute__((address_space(3))) unsigned int*)l, 16, 0, 0);
}

// ---- normalize + bf16 + per-chunk class hist + class column-sums ----
// (R7-proven body; block 0 also zeroes out[0] for the atomic accumulation)
__global__ __launch_bounds__(1024) void k_norm(const float* __restrict__ x,
                                               const int* __restrict__ tgt,
                                               unsigned short* __restrict__ xn,
                                               int* __restrict__ h,
                                               float* __restrict__ cs,
                                               float* __restrict__ out) {
  __shared__ float lx[64][256];    // 64 KB
  __shared__ int lt[64];
  __shared__ int lh[4];
  const int tid = threadIdx.x, w = tid >> 6, lane = tid & 63;
  const int b = blockIdx.x;
  if (b == 0 && tid == 0) out[0] = 0.0f;
  if (tid < 4) lh[tid] = 0;
  if (tid < 64) lt[tid] = tgt[b * 64 + tid];
#pragma unroll
  for (int i = 0; i < 4; ++i) {
    int r = w * 4 + i;
    int row = b * 64 + r;
    float4 v = reinterpret_cast<const float4*>(x)[row * 64 + lane];
    float ss = v.x * v.x + v.y * v.y + v.z * v.z + v.w * v.w;
#pragma unroll
    for (int off = 32; off; off >>= 1) ss += __shfl_xor(ss, off);
    float iv = 1.0f / fmaxf(sqrtf(ss), 1e-8f);
    float4 nv = make_float4(v.x * iv, v.y * iv, v.z * iv, v.w * iv);
    ushort4 o;
    o.x = f2bf(nv.x); o.y = f2bf(nv.y); o.z = f2bf(nv.z); o.w = f2bf(nv.w);
    reinterpret_cast<ushort4*>(xn)[row * 64 + lane] = o;
    *reinterpret_cast<float4*>(&lx[r][lane * 4]) = nv;
  }
  __syncthreads();
  if (tid < 64) atomicAdd(&lh[lt[tid]], 1);
  {
    const int c = tid >> 8, col = tid & 255;
    float m = 0.0f;
#pragma unroll 8
    for (int r = 0; r < 64; ++r)
      m += (lt[r] == c) ? lx[r][col] : 0.0f;
    cs[b * 1024 + tid] = m;
  }
  __syncthreads();
  if (tid < 4) h[b * 4 + tid] = lh[tid];
}

// ---- rectangle GEMM-reduce; per-block partition derivation; atomic out; NO fences ----
__global__ __launch_bounds__(256, 2) void k_main(const char* __restrict__ xnb,
                                                 const int* __restrict__ tgt,
                                                 const int* __restrict__ h,
                                                 const float* __restrict__ cs,
                                                 float* __restrict__ out) {
  __shared__ __align__(16) char sm[65536];     // 2x32KB dbuf
  __shared__ unsigned short hL[128];
  __shared__ int sPL[129];
  __shared__ unsigned short lsA[128], lsB[128];
  __shared__ int scnt4[4];
  __shared__ float wred[4];
  __shared__ float acc8[8];

  const int b = blockIdx.x;
  const int tid = threadIdx.x, w = tid >> 6, lane = tid & 63;

  // ---- prologue: global cnt + L from h (in-block only) ----
  if (tid < 4) scnt4[tid] = 0;
  __syncthreads();
  if (tid < 128) {
    int4 hv = ((const int4*)h)[tid];
    atomicAdd(&scnt4[0], hv.x); atomicAdd(&scnt4[1], hv.y);
    atomicAdd(&scnt4[2], hv.z); atomicAdd(&scnt4[3], hv.w);
  }
  __syncthreads();
  int L = 0;
#pragma unroll
  for (int i = 0; i < 4; ++i) if (scnt4[i] > 0) L = i;
  const int NL = scnt4[L], M = NROWS - NL;
  const int ni = (M + 127) >> 7, nj = (NL + 127) >> 7;
  const int ntiles = ni * nj;

  // ---- exclusive prefix of per-chunk L counts (PN[c] = 64c - PL[c]) ----
  if (tid < 128) {
    int hl = h[tid * 4 + L];
    hL[tid] = (unsigned short)hl;
    sPL[tid + 1] = hl;
  }
  if (tid == 0) sPL[0] = 0;
  __syncthreads();
  for (int ofs = 1; ofs < 128; ofs <<= 1) {
    int v = 0, i = tid + 1;
    bool act = (tid < 128) && (i > ofs);
    if (act) v = sPL[i - ofs];
    __syncthreads();
    if (act) sPL[i] += v;
    __syncthreads();
  }

  // ---- GEMM geometry (R7-verified) ----
  const int rl = lane >> 3;
  const unsigned pe = ((unsigned)((lane & 7) ^ rl)) << 4;
  const int wr = (w >> 1) * 64, wc = (w & 1) * 64;
  const int l15 = lane & 15;
  const unsigned q16 = ((unsigned)(lane >> 4)) << 4;
  const unsigned key = ((unsigned)(lane & 7)) << 4;
  const int rowj = (lane >> 4) * 4;
  char (*lds)[32768] = (char(*)[32768])sm;

  float bsum = 0.0f;
  for (int t = b; t < ntiles; t += NBM) {
    int bi = t / nj, bj = t - bi * nj;
    int rm = min(128, M - bi * 128);
    int rn = min(128, NL - bj * 128);
    bool full = (rm == 128) && (rn == 128);

    // build gather lists (R11-verified ballot-rank scheme)
    if (tid < 128) {
      if (tid >= rm) lsA[tid] = 0;
      if (tid >= rn) lsB[tid] = 0;
    }
    for (int c = w; c < 128; c += 4) {
      int PLc = sPL[c], hLc = hL[c];
      int PNc = c * 64 - PLc, hNc = 64 - hLc;
      bool needA = (PNc < bi * 128 + rm) && (PNc + hNc > bi * 128);
      bool needB = (PLc < bj * 128 + rn) && (PLc + hLc > bj * 128);
      if (needA || needB) {
        int row = c * 64 + lane;
        bool isL = (tgt[row] == L);
        unsigned long long mk = __ballot(isL);
        int rk = __popcll(mk & ((1ull << lane) - 1ull));
        if (isL) {
          int rel = PLc + rk - bj * 128;
          if (rel >= 0 && rel < rn) lsB[rel] = (unsigned short)row;
        } else {
          int rel = PNc + (lane - rk) - bi * 128;
          if (rel >= 0 && rel < rm) lsA[rel] = (unsigned short)row;
        }
      }
    }
    __syncthreads();

    unsigned aoff[4], boff[4];
#pragma unroll
    for (int j = 0; j < 4; ++j) {
      int row = (j * 4 + w) * 8 + rl;
      aoff[j] = (unsigned)lsA[row] * 512u + pe;
      boff[j] = (unsigned)lsB[row] * 512u + pe;
    }

    auto stage = [&](int buf, int ch) {
      unsigned cbo = (unsigned)(ch << 7);
#pragma unroll
      for (int j = 0; j < 4; ++j)
        gl_lds16(xnb + (size_t)(aoff[j] + cbo), &lds[buf][(j * 4 + w) * 1024]);
#pragma unroll
      for (int j = 0; j < 4; ++j)
        gl_lds16(xnb + (size_t)(boff[j] + cbo), &lds[buf][16384 + (j * 4 + w) * 1024]);
    };

    f32x4 acc[4][4];
#pragma unroll
    for (int m = 0; m < 4; ++m)
#pragma unroll
      for (int n = 0; n < 4; ++n)
        acc[m][n] = (f32x4){0.f, 0.f, 0.f, 0.f};

    auto compute = [&](int buf) {
      const char* bA = lds[buf];
      const char* bB = lds[buf] + 16384;
#pragma unroll
      for (int ks = 0; ks < 2; ++ks) {
        const unsigned q = (unsigned)(ks * 64) + q16;
        bf16x8 af[4], bfr[4];
#pragma unroll
        for (int m = 0; m < 4; ++m)
          af[m] = *(const bf16x8*)(bA + (wr + m * 16 + l15) * 128 + (q ^ key));
#pragma unroll
        for (int n = 0; n < 4; ++n)
          bfr[n] = *(const bf16x8*)(bB + (wc + n * 16 + l15) * 128 + (q ^ key));
        __builtin_amdgcn_s_setprio(1);
#pragma unroll
        for (int m = 0; m < 4; ++m)
#pragma unroll
          for (int n = 0; n < 4; ++n)
            acc[m][n] = __builtin_amdgcn_mfma_f32_16x16x32_bf16(af[m], bfr[n], acc[m][n], 0, 0, 0);
        __builtin_amdgcn_s_setprio(0);
      }
    };

    stage(0, 0); stage(1, 1);
    asm volatile("s_waitcnt vmcnt(8)" ::: "memory");
    __builtin_amdgcn_s_barrier();
    compute(0);
    __builtin_amdgcn_s_barrier();
    stage(0, 2);
    asm volatile("s_waitcnt vmcnt(8)" ::: "memory");
    __builtin_amdgcn_s_barrier();
    compute(1);
    __builtin_amdgcn_s_barrier();
    stage(1, 3);
    asm volatile("s_waitcnt vmcnt(8)" ::: "memory");
    __builtin_amdgcn_s_barrier();
    compute(0);
    __builtin_amdgcn_s_barrier();
    asm volatile("s_waitcnt vmcnt(0)" ::: "memory");
    __builtin_amdgcn_s_barrier();
    compute(1);

    if (full) {
#pragma unroll
      for (int m = 0; m < 4; ++m)
#pragma unroll
        for (int n = 0; n < 4; ++n)
#pragma unroll
          for (int j = 0; j < 4; ++j)
            bsum += fmaxf(acc[m][n][j] - 0.5f, 0.0f);
    } else {
#pragma unroll
      for (int m = 0; m < 4; ++m) {
#pragma unroll
        for (int j = 0; j < 4; ++j) {
          bool rv = (wr + m * 16 + rowj + j) < rm;
#pragma unroll
          for (int n = 0; n < 4; ++n) {
            bool cv = (wc + n * 16 + l15) < rn;
            float g = fmaxf(acc[m][n][j] - 0.5f, 0.0f);
            bsum += (rv && cv) ? g : 0.0f;
          }
        }
      }
    }
    __syncthreads();   // protect lsA/lsB + dbuf for next tile
  }

  // ---- per-block: one fp32 atomicAdd of diff partial ----
#pragma unroll
  for (int off = 32; off; off >>= 1) bsum += __shfl_xor(bsum, off);
  if (lane == 0) wred[w] = bsum;
  __syncthreads();
  if (tid == 0)
    atomicAdd(out, (wred[0] + wred[1] + wred[2] + wred[3]) * (1.0f / (float)NROWS));

  // ---- block 0: closed-form same-class term ----
  if (b == 0) {
    float m0 = 0, m1 = 0, m2 = 0, m3 = 0;
    for (int bb = 0; bb < 128; ++bb) {
      const float* p = cs + bb * 1024;
      m0 += p[tid]; m1 += p[256 + tid]; m2 += p[512 + tid]; m3 += p[768 + tid];
    }
    float T = m0 + m1 + m2 + m3;
    float vals[8];
    vals[0] = m0 * m0; vals[1] = m1 * m1; vals[2] = m2 * m2; vals[3] = m3 * m3;
    vals[4] = (T - m0) * (T - m0); vals[5] = (T - m1) * (T - m1);
    vals[6] = (T - m2) * (T - m2); vals[7] = (T - m3) * (T - m3);
#pragma unroll
    for (int v = 0; v < 8; ++v) {
      float sv = vals[v];
#pragma unroll
      for (int off = 32; off; off >>= 1) sv += __shfl_xor(sv, off);
      if (lane == 0) wred[w] = sv;
      __syncthreads();
      if (tid == 0) acc8[v] = wred[0] + wred[1] + wred[2] + wred[3];
      __syncthreads();
    }
    if (tid == 0) {
      double D = (double)NROWS;   // sum of |unit vector|^2
      double same = 0.0;
#pragma unroll
      for (int i = 0; i < 4; ++i) {
        int k = scnt4[i];
        if (k > 0) {
          double Pi = 0.5 * (double)k * (double)(k - 1)
                    + 0.5 * (double)(NROWS - k) * (double)(NROWS - k - 1);
          double Si = 0.5 * ((double)acc8[i] + (double)acc8[4 + i] - D);
          same += (Pi - Si) / (double)k;
        }
      }
      atomicAdd(out, (float)(same / (double)NROWS));
    }
  }
}

extern "C" void kernel_launch(void* const* d_in, const int* in_sizes, int n_in,
                              void* d_out, int out_size, void* d_ws, size_t ws_size,
                              hipStream_t stream) {
  (void)in_sizes; (void)n_in; (void)out_size; (void)ws_size;
  const float* x  = (const float*)d_in[0];
  const int* tgt  = (const int*)d_in[1];
  float* out      = (float*)d_out;
  char* ws        = (char*)d_ws;

  int* h          = (int*)(ws + H_OFF);
  float* cs       = (float*)(ws + CS_OFF);
  unsigned short* xn = (unsigned short*)(ws + XN_OFF);

  k_norm<<<NBN, 1024, 0, stream>>>(x, tgt, xn, h, cs, out);
  k_main<<<NBM, 256, 0, stream>>>((const char*)xn, tgt, h, cs, out);
}